// Round 10
// baseline (244.977 us; speedup 1.0000x reference)
//
#include <hip/hip_runtime.h>

typedef _Float16 half8 __attribute__((ext_vector_type(8)));
typedef float f32x16 __attribute__((ext_vector_type(16)));

// Problem constants
#define EDIM 256
#define NE   1024
#define HW   4096

// d_out layout (fp32 elements): z_q[16777216], loss, perplexity, idx[65536]
#define ZQ_OFF   0
#define LOSS_OFF 16777216
#define PERP_OFF 16777217
#define IDX_OFF  16777218

// ws layout (byte offsets)
#define WS_ESPH    0                         // eh fragment-ordered f16, 512 KB
#define WS_BNORM   (1024*1024)               // 1024 f32
#define WS_COUNTS  (WS_BNORM + 4096)         // 1024 i32
#define WS_COUNTER (WS_COUNTS + 4096)        // i32 (+pad)
#define WS_LOSS    (WS_COUNTER + 16)         // double
#define WS_AN      (WS_LOSS + 16)            // 65536 f32
#define WS_IDX     (WS_AN + 65536*4)         // 65536 i32
#define WS_LIST    (WS_IDX + 65536*4)        // 65536 i32
#define WS_ET      (WS_LIST + 65536*4)       // eT[c][j] f32, 1 MB (16B aligned)

// refine margin in d-units; provable distortion bound ~1.9e-4 (single-term
// split residual 9.6e-5 + numpy fp32 rounding 9.2e-5). 1.6x safety.
#define EPS 3.0e-4f
// g = acc - 512*B_j tracked in max-domain; gap test g1-g2 < 512*EPS
#define GEPS (512.0f * EPS)

#define AS1 __attribute__((address_space(1)))
#define AS3 __attribute__((address_space(3)))

// ---------------------------------------------------------------------------
// K0: e*1024 -> f16 hi, FRAGMENT-ORDERED for 32x32x16 MFMA staging.
// ---------------------------------------------------------------------------
__global__ void k_prep_e(const float* __restrict__ e, _Float16* __restrict__ eh) {
    int t = blockIdx.x * 256 + threadIdx.x;   // 262144
    int j = t >> 8, c = t & 255;
    float v = e[t] * 1024.0f;                 // exact pow2 scale
    _Float16 h = (_Float16)v;
    int jt = j >> 7, nt = (j >> 5) & 3, lm = j & 31;
    int kc = c >> 5, r = c & 31, kh = r >> 4, hb = (r >> 3) & 1, kk = r & 7;
    int chunk = (((jt * 8 + kc) * 4 + nt) * 2 + kh) * 64 + hb * 32 + lm;
    eh[chunk * 8 + kk] = h;
}

// ---------------------------------------------------------------------------
// K0b: fp32 transpose e[j][c] -> eT[c][j] via LDS tile + FUSED Bn.
// 32 j-rows per block, 32 blocks. Bn replayed from the LDS tile with
// numpy's exact 8-accumulator chain -> bit-identical to the old k_bnorm.
// ---------------------------------------------------------------------------
__global__ void k_transpose(const float* __restrict__ e, float* __restrict__ eT,
                            float* __restrict__ Bn) {
    __shared__ float tile[32][257];
    int b = blockIdx.x;            // j-tile [32b, 32b+32)
    int t = threadIdx.x;
#pragma unroll
    for (int i = 0; i < 32; ++i)
        tile[i][t] = e[(size_t)(32 * b + i) * 256 + t];
    __syncthreads();
    int jl = t & 31, cg = t >> 5;  // 8 c-groups of 32 lanes
#pragma unroll
    for (int k = 0; k < 32; ++k) {
        int c = cg * 32 + k;
        eT[(size_t)c * 1024 + 32 * b + jl] = tile[jl][c];
    }
    // fused Bn: 32 rows x 8 lanes; lane q owns accumulator r[q] (c == q mod 8)
    int row = t >> 3, q = t & 7;
    float A[2];
#pragma unroll
    for (int h = 0; h < 2; ++h) {
#pragma clang fp contract(off)
        float acc = 0.f;
        for (int i = 0; i < 16; ++i) {
            float v = tile[row][h * 128 + i * 8 + q];
            float sq = v * v;
            acc = (i == 0) ? sq : acc + sq;
        }
#pragma unroll
        for (int s = 1; s < 8; s <<= 1) acc += __shfl_xor(acc, s, 64);
        A[h] = acc;
    }
    if (q == 0) {
#pragma clang fp contract(off)
        Bn[32 * b + row] = A[0] + A[1];
    }
}

// ---------------------------------------------------------------------------
// K3 v8: MFMA distance + top-2 argmin + loss + histogram + fused rownorm
// + BARRIER-FREE z_q gather tail (direct eT gather).
// 256 blocks x 512 thr (8 waves x 32 rows), v3 staging (2x64 KB dbuf,
// bulk global_load_lds, one __syncthreads per jt).
// Tail: lane L preloads jr[0..3]=idxs[4L..4L+3]; wave w owns c in
// [32w,32w+32); per c: 4 scalar gathers from the 4KB L1-resident eT row,
// one coalesced 1KB/wave float4 store. No LDS staging, no barriers --
// replaces the 32-barrier LDS-transpose tail (was ~59us, TA floor ~7us).
// k_refine patches rows it changes. MFMA order identical -> bit-identical.
// ---------------------------------------------------------------------------
__global__ __launch_bounds__(512, 2) void k_dist(
    const float* __restrict__ z, const _Float16* __restrict__ eh,
    const float* __restrict__ eT, const float* __restrict__ Bn,
    int* __restrict__ idxw, float* __restrict__ out,
    int* __restrict__ counter, int* __restrict__ list,
    double* __restrict__ loss_sum, int* __restrict__ counts,
    float* __restrict__ An)
{
    __shared__ uint4  sB[2][4096];    // 2 x 64 KB (one jt-chunk each)
    __shared__ double lsum[16];
    __shared__ int    lflag[256];
    __shared__ int    idxs[256];
    __shared__ int    lcnt;
    __shared__ int    lbase;

    const int t  = threadIdx.x;       // 0..511
    const int w  = t >> 6;            // 8 waves
    const int L  = t & 63;
    const int l5 = L & 31;
    const int hb = L >> 5;
    const int n0 = blockIdx.x * 256;  // 256 blocks
    const int b  = n0 >> 12, hw0 = n0 & 4095;
    const float* zb = z + (size_t)b * (EDIM * HW) + hw0;
    const int rbase = w * 32;

    if (t == 0) lcnt = 0;

    const uint4* gB4 = (const uint4*)eh;
    const int wb = t & 448;           // w*64: wave-uniform lane-0 slot

    // stage(jt=0) into buf0 -- overlaps with the preamble below
#pragma unroll
    for (int i = 0; i < 8; ++i)
        __builtin_amdgcn_global_load_lds(
            (const AS1 void*)(gB4 + (i * 512 + t)),
            (AS3 void*)(&sB[0][i * 512 + wb]), 16, 0, 0);

    // Preamble: A fragments + fused numpy-exact rownorm (partner-lane shfl).
    half8 Ah[16];
    double aSred;
    {
        int m = rbase + l5;
        float r[8]; float A1 = 0.f, Aval;
#pragma unroll
        for (int ks = 0; ks < 16; ++ks) {
            float av[8], pv[8];
#pragma unroll
            for (int j = 0; j < 8; ++j)
                av[j] = zb[(ks * 16 + hb * 8 + j) * HW + m];
#pragma unroll
            for (int j = 0; j < 8; ++j)
                pv[j] = __shfl_xor(av[j], 32, 64);
            {
#pragma clang fp contract(off)
#pragma unroll
                for (int j = 0; j < 8; ++j) {
                    float a0 = hb ? pv[j] : av[j];   // first in c-order
                    float a1 = hb ? av[j] : pv[j];   // second in c-order
                    if ((ks & 7) == 0) r[j] = a0 * a0;
                    else               r[j] += a0 * a0;
                    r[j] += a1 * a1;
                }
            }
#pragma unroll
            for (int j = 0; j < 8; ++j)
                Ah[ks][j] = (_Float16)av[j];
            if (ks == 7) {
#pragma clang fp contract(off)
                A1 = ((r[0] + r[1]) + (r[2] + r[3])) + ((r[4] + r[5]) + (r[6] + r[7]));
            }
        }
        {
#pragma clang fp contract(off)
            float A2 = ((r[0] + r[1]) + (r[2] + r[3])) + ((r[4] + r[5]) + (r[6] + r[7]));
            Aval = A1 + A2;
        }
        if (hb == 0) An[n0 + m] = Aval;
        double aS = (hb == 0) ? (double)Aval : 0.0;
#pragma unroll
        for (int s = 1; s < 32; s <<= 1) aS += __shfl_xor(aS, s, 64);
        aSred = aS;   // valid (32-row sum) on L==0; 0 on L==32
    }

    f32x16 acc[4];
#pragma unroll
    for (int nt = 0; nt < 4; ++nt)
#pragma unroll
        for (int r = 0; r < 16; ++r) acc[nt][r] = 0.f;

    float g1[16], g2[16]; int i1[16];
#pragma unroll
    for (int r = 0; r < 16; ++r) { g1[r] = -1e30f; g2[r] = -1e30f; i1[r] = 0; }

    __syncthreads();   // jt=0 staged (drain overlapped with preamble)

    for (int jt = 0; jt < 8; ++jt) {
        const int buf = jt & 1;
        if (jt < 7) {
#pragma unroll
            for (int i = 0; i < 8; ++i)
                __builtin_amdgcn_global_load_lds(
                    (const AS1 void*)(gB4 + ((jt + 1) * 4096 + i * 512 + t)),
                    (AS3 void*)(&sB[buf ^ 1][i * 512 + wb]), 16, 0, 0);
        }

        // compute: 64 conflict-free ds_read_b128 + 64 MFMA (order == v3)
#pragma unroll
        for (int kc = 0; kc < 8; ++kc) {
#pragma unroll
            for (int kh = 0; kh < 2; ++kh) {
#pragma unroll
                for (int nt = 0; nt < 4; ++nt) {
                    half8 bh = *(const half8*)&sB[buf][((kc * 4 + nt) * 2 + kh) * 64 + L];
                    acc[nt] = __builtin_amdgcn_mfma_f32_32x32x16_f16(
                        Ah[kc * 2 + kh], bh, acc[nt], 0, 0, 0);
                }
            }
        }

        // fold acc -> top2 (max domain), reset acc
        float en512[4];
#pragma unroll
        for (int nt = 0; nt < 4; ++nt)
            en512[nt] = 512.0f * Bn[jt * 128 + nt * 32 + l5];
#pragma unroll
        for (int nt = 0; nt < 4; ++nt) {
            int jc = jt * 128 + nt * 32 + l5;
#pragma unroll
            for (int r = 0; r < 16; ++r) {
                float v = acc[nt][r] - en512[nt];
                g2[r] = fmaxf(g2[r], fminf(v, g1[r]));   // 2nd-largest
                bool gt = v > g1[r];                     // strict: first idx wins
                g1[r] = fmaxf(v, g1[r]);
                i1[r] = gt ? jc : i1[r];
                acc[nt][r] = 0.f;
            }
        }

        __syncthreads();   // buf[jt^1] fully staged; all waves done with buf
    }

    // cross-lane top2 merge over 32 lanes sharing rows (same hb)
    double lossP = 0.0;
#pragma unroll
    for (int r = 0; r < 16; ++r) {
        float v1 = g1[r], v2 = g2[r]; int ii = i1[r];
#pragma unroll
        for (int s = 1; s < 32; s <<= 1) {
            float o1 = __shfl_xor(v1, s, 64);
            int   oi = __shfl_xor(ii, s, 64);
            float o2 = __shfl_xor(v2, s, 64);
            float lo = fminf(v1, o1);
            if (o1 > v1 || (o1 == v1 && oi < ii)) { v1 = o1; ii = oi; }
            v2 = fmaxf(fmaxf(v2, o2), lo);
        }
        if (l5 == 0) {
            int rloc = rbase + 4 * hb + (r & 3) + 8 * (r >> 2);
            int n = n0 + rloc;
            idxw[n] = ii;
            idxs[rloc] = ii;
            out[IDX_OFF + n] = (float)ii;
            atomicAdd(&counts[ii], 1);
            lossP += -(double)v1 * (1.0 / 512.0);   // d_min = -g1/512
            if (v1 - v2 < GEPS) {
                int p = atomicAdd(&lcnt, 1);        // LDS atomic
                if (p < 256) lflag[p] = n;
            }
        }
    }
    if (l5 == 0) lsum[w * 2 + hb] = lossP + aSred;   // aSred=0 on hb=1 lane
    __syncthreads();
    if (t == 0) {
        double s = 0.0;
#pragma unroll
        for (int i = 0; i < 16; ++i) s += lsum[i];
        atomicAdd(loss_sum, s);
        lbase = lcnt ? atomicAdd(counter, lcnt) : 0;
    }
    __syncthreads();   // idxs complete + visible to all waves
    for (int i = t; i < lcnt; i += 512) {
        int p = lbase + i;
        if (p < 65536) list[p] = lflag[i];
    }

    // ---- z_q tail v2: direct eT gather, zero LDS staging, zero barriers.
    // lane L covers hw 4L..4L+3; wave w covers c in [32w, 32w+32).
    {
        int jr0 = idxs[4 * L + 0];
        int jr1 = idxs[4 * L + 1];
        int jr2 = idxs[4 * L + 2];
        int jr3 = idxs[4 * L + 3];
        float* zqb = out + ZQ_OFF + (size_t)b * (EDIM * HW) + hw0;
#pragma unroll 4
        for (int i = 0; i < 32; ++i) {
            int c = w * 32 + i;
            const float* er = eT + (size_t)c * 1024;   // 4KB row, L1-hot
            float4 v;
            v.x = er[jr0];
            v.y = er[jr1];
            v.z = er[jr2];
            v.w = er[jr3];
            *(float4*)(zqb + (size_t)c * HW + 4 * L) = v;
        }
    }
}

// ---------------------------------------------------------------------------
// K4: numpy-bit-faithful fp32 rescan of flagged rows + histogram delta-fix
// + z_q PATCH for changed rows (k_dist wrote provisional z_q).
// ---------------------------------------------------------------------------
__global__ __launch_bounds__(256, 2) void k_refine(
    const float* __restrict__ z, const float* __restrict__ eT,
    const float* __restrict__ e,
    const float* __restrict__ Bn, const float* __restrict__ An,
    const int* __restrict__ counter, const int* __restrict__ list,
    int* __restrict__ idxw, float* __restrict__ out,
    int* __restrict__ counts)
{
    __shared__ float zs[8][256];
    __shared__ int   ns[8];
    __shared__ float ans[8];
    __shared__ float pv[4][8];
    __shared__ int   pi[4][8];
    __shared__ int   chgN[8], chgJ[8];
    __shared__ int   nchg;
    int t = threadIdx.x;
    int cnt = min(*counter, 65536);
    for (int li0 = blockIdx.x * 8; li0 < cnt; li0 += gridDim.x * 8) {
        int nrows = min(8, cnt - li0);
        __syncthreads();
        if (t < 8) {
            int n = (t < nrows) ? list[li0 + t] : list[li0];
            ns[t] = n; ans[t] = An[n];
        }
        if (t == 255) nchg = 0;
        __syncthreads();
#pragma unroll
        for (int u = 0; u < 8; ++u) {
            int n = ns[u];
            zs[u][t] = z[(size_t)(n >> 12) * (EDIM * HW) + (n & 4095) + t * HW];
        }
        __syncthreads();

        // D[q][r]: dot(e[4t+q], zs[r]) accumulated in c-ascending fmaf order
        float D[4][8];
#pragma unroll
        for (int q = 0; q < 4; ++q)
#pragma unroll
            for (int r = 0; r < 8; ++r) D[q][r] = 0.f;

        for (int c4 = 0; c4 < 64; ++c4) {
            float4 ec[4];                       // codes 4t..4t+3 at c=4*c4+cc
#pragma unroll
            for (int cc = 0; cc < 4; ++cc)
                ec[cc] = *(const float4*)&eT[(size_t)(c4 * 4 + cc) * 1024 + 4 * t];
            float4 zr[8];                       // broadcast ds_read_b128
#pragma unroll
            for (int r = 0; r < 8; ++r)
                zr[r] = *(const float4*)&zs[r][c4 * 4];
#pragma unroll
            for (int cc = 0; cc < 4; ++cc) {
                const float* ep = (const float*)&ec[cc];
#pragma unroll
                for (int r = 0; r < 8; ++r) {
                    float zv = ((const float*)&zr[r])[cc];
                    D[0][r] = __builtin_fmaf(ep[0], zv, D[0][r]);
                    D[1][r] = __builtin_fmaf(ep[1], zv, D[1][r]);
                    D[2][r] = __builtin_fmaf(ep[2], zv, D[2][r]);
                    D[3][r] = __builtin_fmaf(ep[3], zv, D[3][r]);
                }
            }
        }

        float bm[8]; int bi[8];
#pragma unroll
        for (int r = 0; r < 8; ++r) { bm[r] = 1e30f; bi[r] = 1 << 30; }
        float4 bn4 = *(const float4*)&Bn[4 * t];
        {
#pragma clang fp contract(off)
#pragma unroll
            for (int q = 0; q < 4; ++q) {
                float bnj = ((const float*)&bn4)[q];
                int j = 4 * t + q;
#pragma unroll
                for (int r = 0; r < 8; ++r) {
                    float t2 = D[q][r] + D[q][r];
                    float s  = ans[r] + bnj;
                    float d  = s - t2;
                    if (d < bm[r]) { bm[r] = d; bi[r] = j; }   // ascending j: first wins
                }
            }
        }
        int wv = t >> 6, L = t & 63;
#pragma unroll
        for (int r = 0; r < 8; ++r) {
            float v = bm[r]; int ii = bi[r];
#pragma unroll
            for (int s = 1; s < 64; s <<= 1) {
                float ov = __shfl_xor(v, s, 64);
                int   oi = __shfl_xor(ii, s, 64);
                if (ov < v || (ov == v && oi < ii)) { v = ov; ii = oi; }
            }
            if (L == 0) { pv[wv][r] = v; pi[wv][r] = ii; }
        }
        __syncthreads();
        if (t < nrows) {
            float v = pv[0][t]; int ii = pi[0][t];
#pragma unroll
            for (int w2 = 1; w2 < 4; ++w2)
                if (pv[w2][t] < v || (pv[w2][t] == v && pi[w2][t] < ii)) { v = pv[w2][t]; ii = pi[w2][t]; }
            int n = ns[t];
            int old = idxw[n];
            if (old != ii) {
                idxw[n] = ii;
                out[IDX_OFF + n] = (float)ii;
                atomicSub(&counts[old], 1);
                atomicAdd(&counts[ii], 1);
                int p = atomicAdd(&nchg, 1);
                chgN[p] = n; chgJ[p] = ii;
            }
        }
        __syncthreads();
        // z_q patch: 256 threads write c=t for each changed row
        for (int u = 0; u < nchg; ++u) {
            int n = chgN[u], jj = chgJ[u];
            out[ZQ_OFF + (size_t)(n >> 12) * (EDIM * HW) + (size_t)t * HW + (n & 4095)]
                = e[jj * 256 + t];
        }
    }
}

// ---------------------------------------------------------------------------
// K6: finalize scalars
// ---------------------------------------------------------------------------
__global__ void k_final(const int* __restrict__ counts, const double* __restrict__ loss_sum,
                        float* __restrict__ out) {
    __shared__ float sred[4];
    int t = threadIdx.x;
    float s = 0.f;
    for (int qq = 0; qq < 4; ++qq) {
        float p = (float)counts[qq * 256 + t] * (1.0f / 65536.0f);
        s += p * logf(p + 1e-10f);
    }
#pragma unroll
    for (int sh = 1; sh < 64; sh <<= 1) s += __shfl_xor(s, sh, 64);
    if ((t & 63) == 0) sred[t >> 6] = s;
    __syncthreads();
    if (t == 0) {
        out[PERP_OFF] = expf(-(sred[0] + sred[1] + sred[2] + sred[3]));
        out[LOSS_OFF] = (float)(*loss_sum * 1.25 / 16777216.0);
    }
}

extern "C" void kernel_launch(void* const* d_in, const int* in_sizes, int n_in,
                              void* d_out, int out_size, void* d_ws, size_t ws_size,
                              hipStream_t stream) {
    const float* z = (const float*)d_in[0];
    const float* e = (const float*)d_in[1];
    float* out = (float*)d_out;
    char* ws = (char*)d_ws;

    _Float16* eh      = (_Float16*)(ws + WS_ESPH);
    float*    Bn      = (float*)(ws + WS_BNORM);
    int*      counts  = (int*)(ws + WS_COUNTS);
    int*      counter = (int*)(ws + WS_COUNTER);
    double*   loss_sum= (double*)(ws + WS_LOSS);
    float*    An      = (float*)(ws + WS_AN);
    int*      idxw    = (int*)(ws + WS_IDX);
    int*      list    = (int*)(ws + WS_LIST);
    float*    eT      = (float*)(ws + WS_ET);

    // zero counts + counter + loss accumulator (contiguous)
    hipMemsetAsync(ws + WS_COUNTS, 0, 4096 + 16 + 16, stream);

    k_prep_e   <<<1024, 256, 0, stream>>>(e, eh);
    k_transpose<<<32,   256, 0, stream>>>(e, eT, Bn);
    k_dist     <<<256,  512, 0, stream>>>(z, eh, eT, Bn, idxw, out, counter, list, loss_sum, counts, An);
    k_refine   <<<2048, 256, 0, stream>>>(z, eT, e, Bn, An, counter, list, idxw, out, counts);
    k_final    <<<1,    256, 0, stream>>>(counts, loss_sum, out);
}

// Round 11
// 227.003 us; speedup vs baseline: 1.0792x; 1.0792x over previous
//
#include <hip/hip_runtime.h>

typedef _Float16 half8 __attribute__((ext_vector_type(8)));
typedef float f32x16 __attribute__((ext_vector_type(16)));

// Problem constants
#define EDIM 256
#define NE   1024
#define HW   4096

// d_out layout (fp32 elements): z_q[16777216], loss, perplexity, idx[65536]
#define ZQ_OFF   0
#define LOSS_OFF 16777216
#define PERP_OFF 16777217
#define IDX_OFF  16777218

// ws layout (byte offsets)
#define WS_ESPH    0                         // eh fragment-ordered f16, 512 KB
#define WS_BNORM   (1024*1024)               // 1024 f32
#define WS_COUNTS  (WS_BNORM + 4096)         // 1024 i32
#define WS_COUNTER (WS_COUNTS + 4096)        // i32 (+pad)
#define WS_LOSS    (WS_COUNTER + 16)         // double
#define WS_AN      (WS_LOSS + 16)            // 65536 f32
#define WS_IDX     (WS_AN + 65536*4)         // 65536 i32
#define WS_LIST    (WS_IDX + 65536*4)        // 65536 i32
#define WS_ET      (WS_LIST + 65536*4)       // eT[c][j] f32, 1 MB (16B aligned)

// refine margin in d-units; provable distortion bound ~1.9e-4 (single-term
// split residual 9.6e-5 + numpy fp32 rounding 9.2e-5). 1.6x safety.
#define EPS 3.0e-4f
// g = acc - 512*B_j tracked in max-domain; gap test g1-g2 < 512*EPS
#define GEPS (512.0f * EPS)

#define AS1 __attribute__((address_space(1)))
#define AS3 __attribute__((address_space(3)))

// ---------------------------------------------------------------------------
// K0: e*1024 -> f16 hi, FRAGMENT-ORDERED for 32x32x16 MFMA staging.
// ---------------------------------------------------------------------------
__global__ void k_prep_e(const float* __restrict__ e, _Float16* __restrict__ eh) {
    int t = blockIdx.x * 256 + threadIdx.x;   // 262144
    int j = t >> 8, c = t & 255;
    float v = e[t] * 1024.0f;                 // exact pow2 scale
    _Float16 h = (_Float16)v;
    int jt = j >> 7, nt = (j >> 5) & 3, lm = j & 31;
    int kc = c >> 5, r = c & 31, kh = r >> 4, hb = (r >> 3) & 1, kk = r & 7;
    int chunk = (((jt * 8 + kc) * 4 + nt) * 2 + kh) * 64 + hb * 32 + lm;
    eh[chunk * 8 + kk] = h;
}

// ---------------------------------------------------------------------------
// K0b: fp32 transpose e[j][c] -> eT[c][j] via LDS tile + FUSED Bn.
// 32 j-rows per block, 32 blocks. Bn replayed from the LDS tile with
// numpy's exact 8-accumulator chain -> bit-identical to the old k_bnorm.
// ---------------------------------------------------------------------------
__global__ void k_transpose(const float* __restrict__ e, float* __restrict__ eT,
                            float* __restrict__ Bn) {
    __shared__ float tile[32][257];
    int b = blockIdx.x;            // j-tile [32b, 32b+32)
    int t = threadIdx.x;
#pragma unroll
    for (int i = 0; i < 32; ++i)
        tile[i][t] = e[(size_t)(32 * b + i) * 256 + t];
    __syncthreads();
    int jl = t & 31, cg = t >> 5;  // 8 c-groups of 32 lanes
#pragma unroll
    for (int k = 0; k < 32; ++k) {
        int c = cg * 32 + k;
        eT[(size_t)c * 1024 + 32 * b + jl] = tile[jl][c];
    }
    // fused Bn: 32 rows x 8 lanes; lane q owns accumulator r[q] (c == q mod 8)
    int row = t >> 3, q = t & 7;
    float A[2];
#pragma unroll
    for (int h = 0; h < 2; ++h) {
#pragma clang fp contract(off)
        float acc = 0.f;
        for (int i = 0; i < 16; ++i) {
            float v = tile[row][h * 128 + i * 8 + q];
            float sq = v * v;
            acc = (i == 0) ? sq : acc + sq;
        }
#pragma unroll
        for (int s = 1; s < 8; s <<= 1) acc += __shfl_xor(acc, s, 64);
        A[h] = acc;
    }
    if (q == 0) {
#pragma clang fp contract(off)
        Bn[32 * b + row] = A[0] + A[1];
    }
}

// ---------------------------------------------------------------------------
// K3 v9: MFMA distance + top-2 argmin + loss + histogram + fused rownorm
// + PER-WAVE-PRIVATE LDS-transpose z_q tail.
// 256 blocks x 512 thr (8 waves x 32 rows), v3 staging (2x64 KB dbuf,
// bulk global_load_lds, one __syncthreads per jt).
// Tail: wave w owns rows rbase..rbase+31 and a private 16 KB slice of the
// dead sB. Two c-halves of 128: coalesced 256B e-row loads -> XOR-swizzled
// tile (<=2-way bank alias, free) -> 128B-contiguous z_q stores. No
// cross-wave barriers (intra-wave LDS hazards via compiler lgkmcnt), no
// divergent gathers (round-9's ~1 line/cyc TA serialization eliminated).
// k_refine patches rows it changes. MFMA order identical -> bit-identical.
// ---------------------------------------------------------------------------
__global__ __launch_bounds__(512, 2) void k_dist(
    const float* __restrict__ z, const _Float16* __restrict__ eh,
    const float* __restrict__ e, const float* __restrict__ Bn,
    int* __restrict__ idxw, float* __restrict__ out,
    int* __restrict__ counter, int* __restrict__ list,
    double* __restrict__ loss_sum, int* __restrict__ counts,
    float* __restrict__ An)
{
    __shared__ uint4  sB[2][4096];    // 2 x 64 KB (one jt-chunk each)
    __shared__ double lsum[16];
    __shared__ int    lflag[256];
    __shared__ int    idxs[256];
    __shared__ int    lcnt;
    __shared__ int    lbase;

    const int t  = threadIdx.x;       // 0..511
    const int w  = t >> 6;            // 8 waves
    const int L  = t & 63;
    const int l5 = L & 31;
    const int hb = L >> 5;
    const int n0 = blockIdx.x * 256;  // 256 blocks
    const int b  = n0 >> 12, hw0 = n0 & 4095;
    const float* zb = z + (size_t)b * (EDIM * HW) + hw0;
    const int rbase = w * 32;

    if (t == 0) lcnt = 0;

    const uint4* gB4 = (const uint4*)eh;
    const int wb = t & 448;           // w*64: wave-uniform lane-0 slot

    // stage(jt=0) into buf0 -- overlaps with the preamble below
#pragma unroll
    for (int i = 0; i < 8; ++i)
        __builtin_amdgcn_global_load_lds(
            (const AS1 void*)(gB4 + (i * 512 + t)),
            (AS3 void*)(&sB[0][i * 512 + wb]), 16, 0, 0);

    // Preamble: A fragments + fused numpy-exact rownorm (partner-lane shfl).
    half8 Ah[16];
    double aSred;
    {
        int m = rbase + l5;
        float r[8]; float A1 = 0.f, Aval;
#pragma unroll
        for (int ks = 0; ks < 16; ++ks) {
            float av[8], pv[8];
#pragma unroll
            for (int j = 0; j < 8; ++j)
                av[j] = zb[(ks * 16 + hb * 8 + j) * HW + m];
#pragma unroll
            for (int j = 0; j < 8; ++j)
                pv[j] = __shfl_xor(av[j], 32, 64);
            {
#pragma clang fp contract(off)
#pragma unroll
                for (int j = 0; j < 8; ++j) {
                    float a0 = hb ? pv[j] : av[j];   // first in c-order
                    float a1 = hb ? av[j] : pv[j];   // second in c-order
                    if ((ks & 7) == 0) r[j] = a0 * a0;
                    else               r[j] += a0 * a0;
                    r[j] += a1 * a1;
                }
            }
#pragma unroll
            for (int j = 0; j < 8; ++j)
                Ah[ks][j] = (_Float16)av[j];
            if (ks == 7) {
#pragma clang fp contract(off)
                A1 = ((r[0] + r[1]) + (r[2] + r[3])) + ((r[4] + r[5]) + (r[6] + r[7]));
            }
        }
        {
#pragma clang fp contract(off)
            float A2 = ((r[0] + r[1]) + (r[2] + r[3])) + ((r[4] + r[5]) + (r[6] + r[7]));
            Aval = A1 + A2;
        }
        if (hb == 0) An[n0 + m] = Aval;
        double aS = (hb == 0) ? (double)Aval : 0.0;
#pragma unroll
        for (int s = 1; s < 32; s <<= 1) aS += __shfl_xor(aS, s, 64);
        aSred = aS;   // valid (32-row sum) on L==0; 0 on L==32
    }

    f32x16 acc[4];
#pragma unroll
    for (int nt = 0; nt < 4; ++nt)
#pragma unroll
        for (int r = 0; r < 16; ++r) acc[nt][r] = 0.f;

    float g1[16], g2[16]; int i1[16];
#pragma unroll
    for (int r = 0; r < 16; ++r) { g1[r] = -1e30f; g2[r] = -1e30f; i1[r] = 0; }

    __syncthreads();   // jt=0 staged (drain overlapped with preamble)

    for (int jt = 0; jt < 8; ++jt) {
        const int buf = jt & 1;
        if (jt < 7) {
#pragma unroll
            for (int i = 0; i < 8; ++i)
                __builtin_amdgcn_global_load_lds(
                    (const AS1 void*)(gB4 + ((jt + 1) * 4096 + i * 512 + t)),
                    (AS3 void*)(&sB[buf ^ 1][i * 512 + wb]), 16, 0, 0);
        }

        // compute: 64 conflict-free ds_read_b128 + 64 MFMA (order == v3)
#pragma unroll
        for (int kc = 0; kc < 8; ++kc) {
#pragma unroll
            for (int kh = 0; kh < 2; ++kh) {
#pragma unroll
                for (int nt = 0; nt < 4; ++nt) {
                    half8 bh = *(const half8*)&sB[buf][((kc * 4 + nt) * 2 + kh) * 64 + L];
                    acc[nt] = __builtin_amdgcn_mfma_f32_32x32x16_f16(
                        Ah[kc * 2 + kh], bh, acc[nt], 0, 0, 0);
                }
            }
        }

        // fold acc -> top2 (max domain), reset acc
        float en512[4];
#pragma unroll
        for (int nt = 0; nt < 4; ++nt)
            en512[nt] = 512.0f * Bn[jt * 128 + nt * 32 + l5];
#pragma unroll
        for (int nt = 0; nt < 4; ++nt) {
            int jc = jt * 128 + nt * 32 + l5;
#pragma unroll
            for (int r = 0; r < 16; ++r) {
                float v = acc[nt][r] - en512[nt];
                g2[r] = fmaxf(g2[r], fminf(v, g1[r]));   // 2nd-largest
                bool gt = v > g1[r];                     // strict: first idx wins
                g1[r] = fmaxf(v, g1[r]);
                i1[r] = gt ? jc : i1[r];
                acc[nt][r] = 0.f;
            }
        }

        __syncthreads();   // buf[jt^1] fully staged; all waves done with buf
    }

    // cross-lane top2 merge over 32 lanes sharing rows (same hb)
    double lossP = 0.0;
#pragma unroll
    for (int r = 0; r < 16; ++r) {
        float v1 = g1[r], v2 = g2[r]; int ii = i1[r];
#pragma unroll
        for (int s = 1; s < 32; s <<= 1) {
            float o1 = __shfl_xor(v1, s, 64);
            int   oi = __shfl_xor(ii, s, 64);
            float o2 = __shfl_xor(v2, s, 64);
            float lo = fminf(v1, o1);
            if (o1 > v1 || (o1 == v1 && oi < ii)) { v1 = o1; ii = oi; }
            v2 = fmaxf(fmaxf(v2, o2), lo);
        }
        if (l5 == 0) {
            int rloc = rbase + 4 * hb + (r & 3) + 8 * (r >> 2);
            int n = n0 + rloc;
            idxw[n] = ii;
            idxs[rloc] = ii;
            out[IDX_OFF + n] = (float)ii;
            atomicAdd(&counts[ii], 1);
            lossP += -(double)v1 * (1.0 / 512.0);   // d_min = -g1/512
            if (v1 - v2 < GEPS) {
                int p = atomicAdd(&lcnt, 1);        // LDS atomic
                if (p < 256) lflag[p] = n;
            }
        }
    }
    if (l5 == 0) lsum[w * 2 + hb] = lossP + aSred;   // aSred=0 on hb=1 lane
    __syncthreads();
    if (t == 0) {
        double s = 0.0;
#pragma unroll
        for (int i = 0; i < 16; ++i) s += lsum[i];
        atomicAdd(loss_sum, s);
        lbase = lcnt ? atomicAdd(counter, lcnt) : 0;
    }
    __syncthreads();   // idxs complete + visible to all waves
    for (int i = t; i < lcnt; i += 512) {
        int p = lbase + i;
        if (p < 65536) list[p] = lflag[i];
    }

    // ---- z_q tail v3: per-wave-private LDS transpose (barrier-free).
    // Wave w: rows rbase..rbase+31, private 16 KB at tw. Per c-half (128 c):
    //   load: lane L reads e[j][h*128+L] and e[j][h*128+64+L] (256B coalesced)
    //   tile[cl][i] at tw[cl*32 + (i ^ (cl&31))]  (<=2-way alias, free)
    //   store: lane (l5,hb) -> z_q[h*128+cc*2+hb][rbase+l5], 128B runs.
    {
        float* tw = (float*)&sB[0][0] + (size_t)w * 4096;   // 16 KB/wave
        int jw = idxs[rbase + l5];                          // row idx in lane l5
        float* zqb = out + ZQ_OFF + (size_t)b * (EDIM * HW) + hw0;
#pragma unroll
        for (int h = 0; h < 2; ++h) {
            // fill tile: 32 rows x 128 c
            for (int i = 0; i < 32; ++i) {
                int j = __shfl(jw, i, 64);
                const float* er = e + (size_t)j * EDIM + h * 128;
                float v0 = er[L];
                float v1 = er[L + 64];
                tw[L * 32 + (i ^ l5)] = v0;              // cl = L,    cl&31 = l5
                tw[(L + 64) * 32 + (i ^ l5)] = v1;       // cl = L+64, cl&31 = l5
            }
            // drain tile -> z_q: 64 iters x (2 c x 32 rows) per wave-instr
            for (int cc = 0; cc < 64; ++cc) {
                int cl = cc * 2 + hb;
                float val = tw[cl * 32 + (l5 ^ (cl & 31))];
                zqb[(size_t)(h * 128 + cl) * HW + rbase + l5] = val;
            }
        }
    }
}

// ---------------------------------------------------------------------------
// K4: numpy-bit-faithful fp32 rescan of flagged rows + histogram delta-fix
// + z_q PATCH for changed rows (k_dist wrote provisional z_q).
// ---------------------------------------------------------------------------
__global__ __launch_bounds__(256, 2) void k_refine(
    const float* __restrict__ z, const float* __restrict__ eT,
    const float* __restrict__ e,
    const float* __restrict__ Bn, const float* __restrict__ An,
    const int* __restrict__ counter, const int* __restrict__ list,
    int* __restrict__ idxw, float* __restrict__ out,
    int* __restrict__ counts)
{
    __shared__ float zs[8][256];
    __shared__ int   ns[8];
    __shared__ float ans[8];
    __shared__ float pv[4][8];
    __shared__ int   pi[4][8];
    __shared__ int   chgN[8], chgJ[8];
    __shared__ int   nchg;
    int t = threadIdx.x;
    int cnt = min(*counter, 65536);
    for (int li0 = blockIdx.x * 8; li0 < cnt; li0 += gridDim.x * 8) {
        int nrows = min(8, cnt - li0);
        __syncthreads();
        if (t < 8) {
            int n = (t < nrows) ? list[li0 + t] : list[li0];
            ns[t] = n; ans[t] = An[n];
        }
        if (t == 255) nchg = 0;
        __syncthreads();
#pragma unroll
        for (int u = 0; u < 8; ++u) {
            int n = ns[u];
            zs[u][t] = z[(size_t)(n >> 12) * (EDIM * HW) + (n & 4095) + t * HW];
        }
        __syncthreads();

        // D[q][r]: dot(e[4t+q], zs[r]) accumulated in c-ascending fmaf order
        float D[4][8];
#pragma unroll
        for (int q = 0; q < 4; ++q)
#pragma unroll
            for (int r = 0; r < 8; ++r) D[q][r] = 0.f;

        for (int c4 = 0; c4 < 64; ++c4) {
            float4 ec[4];                       // codes 4t..4t+3 at c=4*c4+cc
#pragma unroll
            for (int cc = 0; cc < 4; ++cc)
                ec[cc] = *(const float4*)&eT[(size_t)(c4 * 4 + cc) * 1024 + 4 * t];
            float4 zr[8];                       // broadcast ds_read_b128
#pragma unroll
            for (int r = 0; r < 8; ++r)
                zr[r] = *(const float4*)&zs[r][c4 * 4];
#pragma unroll
            for (int cc = 0; cc < 4; ++cc) {
                const float* ep = (const float*)&ec[cc];
#pragma unroll
                for (int r = 0; r < 8; ++r) {
                    float zv = ((const float*)&zr[r])[cc];
                    D[0][r] = __builtin_fmaf(ep[0], zv, D[0][r]);
                    D[1][r] = __builtin_fmaf(ep[1], zv, D[1][r]);
                    D[2][r] = __builtin_fmaf(ep[2], zv, D[2][r]);
                    D[3][r] = __builtin_fmaf(ep[3], zv, D[3][r]);
                }
            }
        }

        float bm[8]; int bi[8];
#pragma unroll
        for (int r = 0; r < 8; ++r) { bm[r] = 1e30f; bi[r] = 1 << 30; }
        float4 bn4 = *(const float4*)&Bn[4 * t];
        {
#pragma clang fp contract(off)
#pragma unroll
            for (int q = 0; q < 4; ++q) {
                float bnj = ((const float*)&bn4)[q];
                int j = 4 * t + q;
#pragma unroll
                for (int r = 0; r < 8; ++r) {
                    float t2 = D[q][r] + D[q][r];
                    float s  = ans[r] + bnj;
                    float d  = s - t2;
                    if (d < bm[r]) { bm[r] = d; bi[r] = j; }   // ascending j: first wins
                }
            }
        }
        int wv = t >> 6, L = t & 63;
#pragma unroll
        for (int r = 0; r < 8; ++r) {
            float v = bm[r]; int ii = bi[r];
#pragma unroll
            for (int s = 1; s < 64; s <<= 1) {
                float ov = __shfl_xor(v, s, 64);
                int   oi = __shfl_xor(ii, s, 64);
                if (ov < v || (ov == v && oi < ii)) { v = ov; ii = oi; }
            }
            if (L == 0) { pv[wv][r] = v; pi[wv][r] = ii; }
        }
        __syncthreads();
        if (t < nrows) {
            float v = pv[0][t]; int ii = pi[0][t];
#pragma unroll
            for (int w2 = 1; w2 < 4; ++w2)
                if (pv[w2][t] < v || (pv[w2][t] == v && pi[w2][t] < ii)) { v = pv[w2][t]; ii = pi[w2][t]; }
            int n = ns[t];
            int old = idxw[n];
            if (old != ii) {
                idxw[n] = ii;
                out[IDX_OFF + n] = (float)ii;
                atomicSub(&counts[old], 1);
                atomicAdd(&counts[ii], 1);
                int p = atomicAdd(&nchg, 1);
                chgN[p] = n; chgJ[p] = ii;
            }
        }
        __syncthreads();
        // z_q patch: 256 threads write c=t for each changed row
        for (int u = 0; u < nchg; ++u) {
            int n = chgN[u], jj = chgJ[u];
            out[ZQ_OFF + (size_t)(n >> 12) * (EDIM * HW) + (size_t)t * HW + (n & 4095)]
                = e[jj * 256 + t];
        }
    }
}

// ---------------------------------------------------------------------------
// K6: finalize scalars
// ---------------------------------------------------------------------------
__global__ void k_final(const int* __restrict__ counts, const double* __restrict__ loss_sum,
                        float* __restrict__ out) {
    __shared__ float sred[4];
    int t = threadIdx.x;
    float s = 0.f;
    for (int qq = 0; qq < 4; ++qq) {
        float p = (float)counts[qq * 256 + t] * (1.0f / 65536.0f);
        s += p * logf(p + 1e-10f);
    }
#pragma unroll
    for (int sh = 1; sh < 64; sh <<= 1) s += __shfl_xor(s, sh, 64);
    if ((t & 63) == 0) sred[t >> 6] = s;
    __syncthreads();
    if (t == 0) {
        out[PERP_OFF] = expf(-(sred[0] + sred[1] + sred[2] + sred[3]));
        out[LOSS_OFF] = (float)(*loss_sum * 1.25 / 16777216.0);
    }
}

extern "C" void kernel_launch(void* const* d_in, const int* in_sizes, int n_in,
                              void* d_out, int out_size, void* d_ws, size_t ws_size,
                              hipStream_t stream) {
    const float* z = (const float*)d_in[0];
    const float* e = (const float*)d_in[1];
    float* out = (float*)d_out;
    char* ws = (char*)d_ws;

    _Float16* eh      = (_Float16*)(ws + WS_ESPH);
    float*    Bn      = (float*)(ws + WS_BNORM);
    int*      counts  = (int*)(ws + WS_COUNTS);
    int*      counter = (int*)(ws + WS_COUNTER);
    double*   loss_sum= (double*)(ws + WS_LOSS);
    float*    An      = (float*)(ws + WS_AN);
    int*      idxw    = (int*)(ws + WS_IDX);
    int*      list    = (int*)(ws + WS_LIST);
    float*    eT      = (float*)(ws + WS_ET);

    // zero counts + counter + loss accumulator (contiguous)
    hipMemsetAsync(ws + WS_COUNTS, 0, 4096 + 16 + 16, stream);

    k_prep_e   <<<1024, 256, 0, stream>>>(e, eh);
    k_transpose<<<32,   256, 0, stream>>>(e, eT, Bn);
    k_dist     <<<256,  512, 0, stream>>>(z, eh, e, Bn, idxw, out, counter, list, loss_sum, counts, An);
    k_refine   <<<2048, 256, 0, stream>>>(z, eT, e, Bn, An, counter, list, idxw, out, counts);
    k_final    <<<1,    256, 0, stream>>>(counts, loss_sum, out);
}